// Round 15
// baseline (197.148 us; speedup 1.0000x reference)
//
#include <hip/hip_runtime.h>
#include <hip/hip_fp16.h>
#include <string.h>

// ---------------- problem constants ----------------
#define T_LEN   809
#define DD      304
#define EE      300
#define LQ      30
#define NCAND   12824      // candidates per batch
#define NPAD    12928      // 101 * 128 (padded rows per batch)
#define CIN     1212
#define H1      1024
#define H2      512
#define BATCH   4
#define MROWS_F (BATCH * NPAD)          // 51712 fused rows
#define KS      320                     // 304 padded to mult of 32 (scan-GEMM K)
#define TPAD    3328                    // 26 * 128
#define NROWS_U 3240                    // 4 * 810 valid U-table rows

// mega-prep block ranges (R9: scan tchunk=64 -> 208 scan blocks)
#define MP_W1      208        // scan: 2 dchunk x (13 tchunk x 4 b x 2 dir)
#define MP_W2      4048       // + 3840 (W1 split)
#define MP_BIAS2   6096       // + 2048 (W2 fold)
#define MP_BASE    6098       // + 2
#define MP_RMAP    7122       // + 1024 (baseW)
#define MP_TOTAL   7324       // + 202 (rowmap)

// alpha^(span+1), span in [0,16)
__device__ __constant__ float c_coef[16] = {
  0.9f, 0.81f, 0.729f, 0.6561f, 0.59049f, 0.531441f, 0.4782969f, 0.43046721f,
  0.387420489f, 0.3486784401f, 0.31381059609f, 0.282429536481f,
  0.2541865828329f, 0.22876792454961f, 0.205891132094649f, 0.1853020188851841f
};

// fp16 conversion (R7: whole U-pipeline is fp16)
__device__ __forceinline__ unsigned short f2h(float f) {
  const __half h = __float2half(f);
  return __half_as_ushort(h);
}
// fused combine: relu(ul + ue - cf*uc) on a fp16x2 word; ncf2 = pack2(-cf)
__device__ __forceinline__ unsigned int comb2h(unsigned int ul, unsigned int uc,
                                               unsigned int ue, __half2 ncf2) {
  const __half2 t = __hfma2(*reinterpret_cast<const __half2*>(&uc), ncf2,
                            *reinterpret_cast<const __half2*>(&ue));   // ue - cf*uc
  const __half2 r = __hadd2(*reinterpret_cast<const __half2*>(&ul), t);
  unsigned int ru = *reinterpret_cast<const unsigned int*>(&r);
  ru &= ~(((ru >> 15) & 0x10001u) * 0xFFFFu);   // packed relu (sign-bit mask)
  return ru;
}

typedef const __attribute__((address_space(1))) unsigned int GU32;
typedef __attribute__((address_space(3))) unsigned int LU32;
__device__ __forceinline__ void async16(const unsigned short* g, unsigned short* l) {
  __builtin_amdgcn_global_load_lds((GU32*)g, (LU32*)l, 16, 0, 0);
}

// ---------------- mega prep: scan + W1 split + W2 fold + bias2 + baseW + rowmap ----------------
__global__ __launch_bounds__(256) void k_prep(const float* __restrict__ doc,
                                              const float* __restrict__ qe,
                                              const float* __restrict__ W1,
                                              const float* __restrict__ g1,
                                              const float* __restrict__ b1,
                                              const float* __restrict__ m1,
                                              const float* __restrict__ v1,
                                              const float* __restrict__ W2,
                                              const float* __restrict__ g2,
                                              const float* __restrict__ b2,
                                              const float* __restrict__ m2,
                                              const float* __restrict__ v2,
                                              unsigned short* __restrict__ Fz,
                                              unsigned short* __restrict__ Rz,
                                              unsigned short* __restrict__ Wlc,
                                              unsigned short* __restrict__ Wr,
                                              unsigned short* __restrict__ W2b,
                                              float* __restrict__ bias2,
                                              float* __restrict__ baseW,
                                              unsigned int* __restrict__ rowmap)
{
  __shared__ float qs[EE];
  const int vb  = blockIdx.x;
  const int tid = threadIdx.x;

  if (vb < MP_W1) {
    // ---- scan section (tchunk=64; lookback/output loops split) ----
    const int dchunk = vb & 1;
    const int rest   = vb >> 1;            // 0..103
    const int tchunk = rest % 13;
    const int b      = (rest / 13) & 3;
    const int dir    = rest / 52;
    const int d  = dchunk * 256 + tid;     // 0..511 (valid < 320)
    const int t0 = tchunk * 64;
    if (dir == 0) {
      if (tchunk == 0 && d < KS) Fz[((size_t)b * 810) * KS + d] = 0;   // zero row
      if (d >= DD) return;
      const float* db = doc + (size_t)b * T_LEN * DD + d;
      int start = t0 - 96; if (start < 0) start = 0;
      int end = t0 + 63; if (end > T_LEN - 1) end = T_LEN - 1;
      float s = 0.f;
      int t = start;
      #pragma unroll 4
      for (; t < t0; ++t) s = fmaf(0.9f, s, db[(size_t)t * DD]);       // lookback, no stores
      #pragma unroll 4
      for (; t <= end; ++t) {
        s = fmaf(0.9f, s, db[(size_t)t * DD]);
        Fz[((size_t)b * 810 + 1 + t) * KS + d] = f2h(s);
      }
    } else {
      if (tchunk == 0 && d < KS) Rz[((size_t)b * 810 + 809) * KS + d] = 0;  // zero row
      if (d >= DD) return;
      const float* db = doc + (size_t)b * T_LEN * DD + d;
      int t1 = t0 + 63; if (t1 > T_LEN - 1) t1 = T_LEN - 1;
      int start = t1 + 96; if (start > T_LEN - 1) start = T_LEN - 1;
      float s = 0.f;
      int t = start;
      #pragma unroll 4
      for (; t > t1; --t) s = fmaf(0.9f, s, db[(size_t)t * DD]);       // lookback, no stores
      #pragma unroll 4
      for (; t >= t0; --t) {
        s = fmaf(0.9f, s, db[(size_t)t * DD]);
        Rz[((size_t)b * 810 + t) * KS + d] = f2h(s);
      }
    }
  } else if (vb < MP_W2) {
    // ---- W1 split: flat over 3072 x 320 ----
    const int e = (vb - MP_W1) * 256 + tid;
    const int j = e / KS;                  // 0..3071
    const int k = e - j * KS;              // 0..319
    int jj, koff; unsigned short* dst; size_t idx;
    if (j < 1024)      { jj = j;        koff = k;       dst = Wlc; idx = (size_t)j * KS + k; }
    else if (j < 2048) { jj = j - 1024; koff = 304 + k; dst = Wlc; idx = (size_t)j * KS + k; }
    else               { jj = j - 2048; koff = 608 + k; dst = Wr;  idx = (size_t)(j - 2048) * KS + k; }
    float w = 0.f;
    if (k < 304) w = W1[(size_t)jj * CIN + koff] * g1[jj] * rsqrtf(v1[jj] + 1e-5f);
    dst[idx] = f2h(w);
  } else if (vb < MP_BIAS2) {
    // ---- W2 fold: flat over 512 x 1024 ----
    const int e = (vb - MP_W2) * 256 + tid;
    const int j = e >> 10;
    const int k = e & 1023;
    const float w = W2[(size_t)j * H1 + k] * g2[j] * rsqrtf(v2[j] + 1e-5f);
    W2b[(size_t)j * H1 + k] = f2h(w);
  } else if (vb < MP_BASE) {
    // ---- bias2 ----
    const int i = (vb - MP_BIAS2) * 256 + tid;
    if (i < H2) {
      const float s = g2[i] * rsqrtf(v2[i] + 1e-5f);
      bias2[i] = b2[i] - m2[i] * s;
    }
  } else if (vb < MP_RMAP) {
    // ---- baseW (2048-wide, cand half zero): 1024 blocks = (b, jg) ----
    const int flat = vb - MP_BASE;
    const int b  = flat >> 8;
    const int jg = flat & 255;
    const float* q = qe + (size_t)b * LQ * EE;
    for (int k = tid; k < EE; k += 256) {
      float s = 0.f;
      for (int t = 0; t < LQ; ++t) s = fmaf(s, 0.9f, q[(size_t)t * EE + k]);
      qs[k] = s;
    }
    __syncthreads();
    const int wv   = tid >> 6;
    const int lane = tid & 63;
    const int j = jg * 4 + wv;             // 0..1023
    const float* w = W1 + (size_t)j * CIN + 912;
    float acc = 0.f;
    for (int k = lane; k < EE; k += 64) acc = fmaf(qs[k], w[k], acc);
    #pragma unroll
    for (int off = 32; off; off >>= 1) acc += __shfl_down(acc, off);
    if (lane == 0) {
      const float sc = g1[j] * rsqrtf(v1[j] + 1e-5f);
      baseW[(size_t)b * 2048 + j]        = b1[j] - m1[j] * sc + acc * sc;
      baseW[(size_t)b * 2048 + 1024 + j] = 0.f;
    }
  } else {
    // ---- rowmap: candidate row -> (srow 12b | erow 12b | span 4b) ----
    const int g = (vb - MP_RMAP) * 256 + tid;   // < 51712 (202*256 exact)
    const int b  = g / NPAD;
    const int rr = g - b * NPAD;
    unsigned int mv = 0;                        // padding rows -> row 0 (finite)
    if (rr < NCAND) {
      int s, span;
      if (rr < 12704) { s = rr >> 4; span = rr & 15; }
      else {
        const int x = rr - 12704;
        int d = 0;
        while (d < 14 && x >= (15 * (d + 1) - ((d + 1) * d) / 2)) ++d;
        span = x - (15 * d - (d * (d - 1)) / 2);
        s = 794 + d;
      }
      const unsigned int srow = (unsigned int)(b * 810 + s);
      const unsigned int erow = (unsigned int)(b * 810 + s + span + 1);
      mv = srow | (erow << 12) | ((unsigned int)span << 24);
    }
    rowmap[g] = mv;
  }
}

// ---------------- GEMM machinery ----------------
typedef __attribute__((ext_vector_type(8))) short frag8;
typedef __attribute__((ext_vector_type(4))) float f32x4;

// =====================================================================
// k_ugemm (retry of R12, byte-identical): U-table GEMMs with k_ucr
// MERGED.  Grid 416: blocks 0..207 = UL (UF cols 0..1023, A=Fz
// B=Wlc[0:1024], baseW added -- the R8/R9-proven path).  Blocks
// 208..415 = PAIRED: 20-step parity-interleaved K-loop (even steps
// Fz x Wlc[1024+..] -> accF = UC tile; odd steps Rz x Wr -> accR = UR
// tile; buffer b always holds parity-b data, prefetch distance 1, R8
// dbuf/raw-barrier/vmcnt(0)-pre-barrier discipline).  Paired epilogue
// writes UC into UF (baseW cand half is zero -> no add) and
// UCR = f2h(UC+UR), both via the R9 LDS-staged coalescing.
// R11 FIX: UCR allocated with TPAD rows (NROWS_U sizing overflowed
// into rowmap -> absmax 7209).
// R12 FIX: epilogue ccolb includes the wave column term wn*64 (its
// omission left cols 64..127 of every tile garbage -> absmax 34).
// R14 audit: all address streams bounds-verified twice; prior core
// dump attributed to infra (no bad-address path exists).
// =====================================================================
__global__ __launch_bounds__(256) void k_ugemm(const unsigned short* __restrict__ Fz,
                                               const unsigned short* __restrict__ Wlc,
                                               const unsigned short* __restrict__ Rz,
                                               const unsigned short* __restrict__ Wr,
                                               const float* __restrict__ baseW,
                                               unsigned short* __restrict__ UF,
                                               unsigned short* __restrict__ UCR)
{
  __shared__ __align__(16) unsigned short As[2 * 128 * 32];
  __shared__ __align__(16) unsigned short Bs[2 * 128 * 32];
  const int tid  = threadIdx.x;
  const int lane = tid & 63;
  const int wv   = tid >> 6;
  const int wm   = wv & 1, wn = wv >> 1;
  const int lr = lane >> 2;
  const int lc = lane & 3;
  const int sc = lc ^ ((lr >> 1) & 3);
  const int arow = lane & 15;
  const int pg   = (lane >> 4) ^ ((arow >> 1) & 3);
  const int aoff = (wm * 64 + arow) * 32 + pg * 8;
  const int boff = (wn * 64 + arow) * 32 + pg * 8;
  const size_t row16 = (size_t)16 * KS;
  // epilogue helpers (R9 staging; ccolb includes wn*64)
  const int grp = lane >> 4, rowl = lane >> 2, cg = (lane & 3) * 16;
  unsigned short* scr = &As[wv * 1152];   // 16 rows x 72 shorts per wave

  int bx = blockIdx.x;
  const int paired = bx >= 208;
  if (paired) bx -= 208;
  const int bm = bx >> 3, bn = bx & 7;
  const size_t aro = ((size_t)bm * 128 + wv * 32 + lr) * KS + sc * 8;

  if (!paired) {
    // ---------------- UL path (proven R8 pipeline, 10 steps) ----------------
    const unsigned short* gA = Fz  + aro;
    const unsigned short* gB = Wlc + ((size_t)(bn * 128) + wv * 32 + lr) * KS + sc * 8;
    f32x4 acc[4][4];
    #pragma unroll
    for (int i = 0; i < 4; ++i)
      #pragma unroll
      for (int j = 0; j < 4; ++j) acc[i][j] = (f32x4){0.f, 0.f, 0.f, 0.f};
    async16(gA,         &As[wv * 1024]);
    async16(gA + row16, &As[wv * 1024 + 512]);
    async16(gB,         &Bs[wv * 1024]);
    async16(gB + row16, &Bs[wv * 1024 + 512]);
    asm volatile("s_waitcnt vmcnt(0)" ::: "memory");
    __builtin_amdgcn_sched_barrier(0);
    for (int kc = 0; kc < KS; kc += 32) {
      const int cb = (kc >> 5) & 1, nb = cb ^ 1;
      __builtin_amdgcn_s_barrier();
      __builtin_amdgcn_sched_barrier(0);
      if (kc + 32 < KS) {
        async16(gA + kc + 32,         &As[nb * 4096 + wv * 1024]);
        async16(gA + kc + 32 + row16, &As[nb * 4096 + wv * 1024 + 512]);
        async16(gB + kc + 32,         &Bs[nb * 4096 + wv * 1024]);
        async16(gB + kc + 32 + row16, &Bs[nb * 4096 + wv * 1024 + 512]);
      }
      __builtin_amdgcn_sched_barrier(0);
      frag8 a[4], b[4];
      #pragma unroll
      for (int i = 0; i < 4; ++i) a[i] = *(const frag8*)&As[cb * 4096 + aoff + i * 512];
      #pragma unroll
      for (int i = 0; i < 4; ++i) b[i] = *(const frag8*)&Bs[cb * 4096 + boff + i * 512];
      __builtin_amdgcn_s_setprio(1);
      #pragma unroll
      for (int i = 0; i < 4; ++i)
        #pragma unroll
        for (int j = 0; j < 4; ++j)
          acc[i][j] = __builtin_amdgcn_mfma_f32_16x16x32_f16(a[i], b[j], acc[i][j], 0, 0, 0);
      __builtin_amdgcn_s_setprio(0);
      __builtin_amdgcn_sched_barrier(0);
      if (kc + 32 < KS) { asm volatile("s_waitcnt vmcnt(0)" ::: "memory"); }
      __builtin_amdgcn_sched_barrier(0);
    }
    // epilogue: UF cols 0..1023 with baseW (R9 coalesced staging)
    __syncthreads();
    const int ccolb = bn * 128 + wn * 64;
    #pragma unroll
    for (int i = 0; i < 4; ++i) {
      #pragma unroll
      for (int j = 0; j < 4; ++j)
        #pragma unroll
        for (int r = 0; r < 4; ++r) {
          const int col = ccolb + j * 16 + arow;
          const int row = bm * 128 + wm * 64 + grp * 4 + i * 16 + r;
          int bb = row / 810; if (bb > 3) bb = 3;   // clamp padded rows
          scr[(grp * 4 + r) * 72 + j * 16 + arow] = f2h(acc[i][j][r] + baseW[(size_t)bb * 2048 + col]);
        }
      asm volatile("s_waitcnt lgkmcnt(0)" ::: "memory");
      __builtin_amdgcn_sched_barrier(0);
      const uint4 w0 = *(const uint4*)&scr[rowl * 72 + cg];
      const uint4 w1 = *(const uint4*)&scr[rowl * 72 + cg + 8];
      const size_t grow = (size_t)(bm * 128 + wm * 64 + i * 16 + rowl) * 2048 + ccolb + cg;
      *(uint4*)&UF[grow]     = w0;
      *(uint4*)&UF[grow + 8] = w1;
      __builtin_amdgcn_sched_barrier(0);
    }
  } else {
    // ---------------- paired path: UC (even) + UR (odd), 20 steps ----------------
    const unsigned short* gAF = Fz  + aro;
    const unsigned short* gAR = Rz  + aro;
    const unsigned short* gBL = Wlc + ((size_t)(1024 + bn * 128) + wv * 32 + lr) * KS + sc * 8;
    const unsigned short* gBR = Wr  + ((size_t)(bn * 128) + wv * 32 + lr) * KS + sc * 8;
    f32x4 accF[4][4], accR[4][4];
    #pragma unroll
    for (int i = 0; i < 4; ++i)
      #pragma unroll
      for (int j = 0; j < 4; ++j) {
        accF[i][j] = (f32x4){0.f, 0.f, 0.f, 0.f};
        accR[i][j] = (f32x4){0.f, 0.f, 0.f, 0.f};
      }
    // prologue: step 0 (F parity) -> buf0
    async16(gAF,         &As[wv * 1024]);
    async16(gAF + row16, &As[wv * 1024 + 512]);
    async16(gBL,         &Bs[wv * 1024]);
    async16(gBL + row16, &Bs[wv * 1024 + 512]);
    asm volatile("s_waitcnt vmcnt(0)" ::: "memory");
    __builtin_amdgcn_sched_barrier(0);
    #pragma unroll 2
    for (int s = 0; s < 20; ++s) {
      const int cb = s & 1, nb = cb ^ 1;
      __builtin_amdgcn_s_barrier();
      __builtin_amdgcn_sched_barrier(0);
      if (s < 19) {
        const int kn = ((s + 1) >> 1) * 32;
        const unsigned short* a_ = ((s + 1) & 1) ? gAR : gAF;
        const unsigned short* b_ = ((s + 1) & 1) ? gBR : gBL;
        async16(a_ + kn,         &As[nb * 4096 + wv * 1024]);
        async16(a_ + kn + row16, &As[nb * 4096 + wv * 1024 + 512]);
        async16(b_ + kn,         &Bs[nb * 4096 + wv * 1024]);
        async16(b_ + kn + row16, &Bs[nb * 4096 + wv * 1024 + 512]);
      }
      __builtin_amdgcn_sched_barrier(0);
      frag8 a[4], b[4];
      #pragma unroll
      for (int i = 0; i < 4; ++i) a[i] = *(const frag8*)&As[cb * 4096 + aoff + i * 512];
      #pragma unroll
      for (int i = 0; i < 4; ++i) b[i] = *(const frag8*)&Bs[cb * 4096 + boff + i * 512];
      __builtin_amdgcn_s_setprio(1);
      if (s & 1) {
        #pragma unroll
        for (int i = 0; i < 4; ++i)
          #pragma unroll
          for (int j = 0; j < 4; ++j)
            accR[i][j] = __builtin_amdgcn_mfma_f32_16x16x32_f16(a[i], b[j], accR[i][j], 0, 0, 0);
      } else {
        #pragma unroll
        for (int i = 0; i < 4; ++i)
          #pragma unroll
          for (int j = 0; j < 4; ++j)
            accF[i][j] = __builtin_amdgcn_mfma_f32_16x16x32_f16(a[i], b[j], accF[i][j], 0, 0, 0);
      }
      __builtin_amdgcn_s_setprio(0);
      __builtin_amdgcn_sched_barrier(0);
      if (s < 19) { asm volatile("s_waitcnt vmcnt(0)" ::: "memory"); }
      __builtin_amdgcn_sched_barrier(0);
    }
    // epilogue: UC -> UF[1024+], UCR = f2h(UC+UR) (no baseW: cand half is zero)
    __syncthreads();
    const int ccolb = bn * 128 + wn * 64;
    #pragma unroll
    for (int i = 0; i < 4; ++i) {
      // pass 1: UC
      #pragma unroll
      for (int j = 0; j < 4; ++j)
        #pragma unroll
        for (int r = 0; r < 4; ++r)
          scr[(grp * 4 + r) * 72 + j * 16 + arow] = f2h(accF[i][j][r]);
      asm volatile("s_waitcnt lgkmcnt(0)" ::: "memory");
      __builtin_amdgcn_sched_barrier(0);
      {
        const uint4 w0 = *(const uint4*)&scr[rowl * 72 + cg];
        const uint4 w1 = *(const uint4*)&scr[rowl * 72 + cg + 8];
        const size_t grow = (size_t)(bm * 128 + wm * 64 + i * 16 + rowl) * 2048 + 1024 + ccolb + cg;
        *(uint4*)&UF[grow]     = w0;
        *(uint4*)&UF[grow + 8] = w1;
      }
      __builtin_amdgcn_sched_barrier(0);
      // pass 2: UCR
      #pragma unroll
      for (int j = 0; j < 4; ++j)
        #pragma unroll
        for (int r = 0; r < 4; ++r)
          scr[(grp * 4 + r) * 72 + j * 16 + arow] = f2h(accF[i][j][r] + accR[i][j][r]);
      asm volatile("s_waitcnt lgkmcnt(0)" ::: "memory");
      __builtin_amdgcn_sched_barrier(0);
      {
        const uint4 w0 = *(const uint4*)&scr[rowl * 72 + cg];
        const uint4 w1 = *(const uint4*)&scr[rowl * 72 + cg + 8];
        const size_t grow = (size_t)(bm * 128 + wm * 64 + i * 16 + rowl) * 1024 + ccolb + cg;
        *(uint4*)&UCR[grow]     = w0;
        *(uint4*)&UCR[grow + 8] = w1;
      }
      __builtin_amdgcn_sched_barrier(0);
    }
  }
}

// =====================================================================
// GEMM2 fused with combine (R7 structure, proven): 128x256 tile,
// 8 waves of 64x64, fp16 packed combine, 2 blocks/CU (64 VGPR + 64 AGPR
// = exactly the 128-reg/16-wave cliff -- do NOT add registers here),
// LDS 48 KiB dbuf, race-free counted-vmcnt pipeline, grid 808 = 8*101.
// Epilogue atomicAdds bn-partials directly into out (reset() zeroes out).
// =====================================================================
__global__ __launch_bounds__(512, 4) void k_gemm2f(const unsigned short* __restrict__ UF,
                                                   const unsigned short* __restrict__ UCR,
                                                   const unsigned short* __restrict__ W2b,
                                                   const unsigned int* __restrict__ rowmap,
                                                   const float* __restrict__ bias,
                                                   const float* __restrict__ W3,
                                                   float* __restrict__ out)
{
  __shared__ __align__(16) unsigned short As2[2 * 128 * 32];   // 16 KiB dbuf
  __shared__ __align__(16) unsigned short Bs2[2 * 256 * 32];   // 32 KiB dbuf

  // XCD swizzle: nwg = 808 = 8*101 exact
  const int orig = blockIdx.x;
  const int wg = (orig & 7) * 101 + (orig >> 3);
  const int bm = wg >> 1, bn = wg & 1;

  const int tid  = threadIdx.x;
  const int lane = tid & 63;
  const int w    = tid >> 6;
  const int wm   = w & 1;          // row half (64 rows)
  const int wn   = w >> 1;         // col quarter (64 cols of 256)
  const int arow = lane & 15;
  const int lr   = lane >> 2;
  const int lc   = lane & 3;
  const int sc   = lc ^ ((lr >> 1) & 3);

  // ---- A combine-staging: thread covers row rA = tid>>2, logical chunk cA
  const int rA    = tid >> 2;                  // 0..127
  const int cA    = tid & 3;
  const int physA = cA ^ ((rA >> 1) & 3);
  const unsigned int mv = rowmap[bm * 128 + rA];
  const __half2 ncf2 = __float2half2_rn(-c_coef[mv >> 24]);
  const unsigned short* pUL = UF  + (size_t)(mv & 4095) * 2048 + cA * 8;
  const unsigned short* pUE = UCR + (size_t)((mv >> 12) & 4095) * 1024 + cA * 8;

  // ---- B staging: wave w stages W2b rows bn*256 + w*32 .. +31 (2 async16/lane)
  const unsigned short* gB = W2b + ((size_t)(bn * 256 + w * 32 + lr)) * H1 + sc * 8;

  // ---- fragment read offsets (proven swizzle-reader formulas)
  const int pg   = (lane >> 4) ^ ((arow >> 1) & 3);
  const int aoff = (wm * 64 + arow) * 32 + pg * 8;
  const int boff = (wn * 64 + arow) * 32 + pg * 8;

  f32x4 acc[4][4];
  #pragma unroll
  for (int i = 0; i < 4; ++i)
    #pragma unroll
    for (int j = 0; j < 4; ++j) acc[i][j] = (f32x4){0.f, 0.f, 0.f, 0.f};

  // ---- prologue: g(0), a16 B(0)->buf0, combine(0)->buf0, g(1), drain a16(0) ----
  uint4 vulN = *(const uint4*)(pUL);
  uint4 vucN = *(const uint4*)(pUL + 1024);
  uint4 vueN = *(const uint4*)(pUE);
  {
    unsigned short* lB = &Bs2[w * 1024];
    async16(gB,           lB);
    async16(gB + 16 * H1, lB + 512);
  }
  {
    uint4 o;                                   // use of vulN forces wait for g(0)
    o.x = comb2h(vulN.x, vucN.x, vueN.x, ncf2);
    o.y = comb2h(vulN.y, vucN.y, vueN.y, ncf2);
    o.z = comb2h(vulN.z, vucN.z, vueN.z, ncf2);
    o.w = comb2h(vulN.w, vucN.w, vueN.w, ncf2);
    *(uint4*)&As2[rA * 32 + physA * 8] = o;
  }
  vulN = *(const uint4*)(pUL + 32);            // g(1)
  vucN = *(const uint4*)(pUL + 1024 + 32);
  vueN = *(const uint4*)(pUE + 32);
  asm volatile("s_waitcnt vmcnt(3) lgkmcnt(0)" ::: "memory");  // a16(0) landed, ds_write done
  __builtin_amdgcn_sched_barrier(0);

  // ---- main loop: entering step k, outstanding = g(k+1) x3 (or 0 at k=31);
  //      all a16(k) drained pre-barrier -> reads after barrier are race-free.
  for (int k = 0; k < 32; ++k) {
    const int cur = k & 1, nxt = cur ^ 1;
    __builtin_amdgcn_s_barrier();
    __builtin_amdgcn_sched_barrier(0);
    if (k < 31) {
      const int kn = (k + 1) * 32;
      unsigned short* lB = &Bs2[nxt * 8192 + w * 1024];
      async16(gB + kn,           lB);
      async16(gB + kn + 16 * H1, lB + 512);
      __builtin_amdgcn_sched_barrier(0);
      asm volatile("s_waitcnt vmcnt(2)" ::: "memory");   // g(k+1) landed; a16(k+1) flying
      __builtin_amdgcn_sched_barrier(0);
      uint4 o;
      o.x = comb2h(vulN.x, vucN.x, vueN.x, ncf2);
      o.y = comb2h(vulN.y, vucN.y, vueN.y, ncf2);
      o.z = comb2h(vulN.z, vucN.z, vueN.z, ncf2);
      o.w = comb2h(vulN.w, vucN.w, vueN.w, ncf2);
      *(uint4*)&As2[nxt * 4096 + rA * 32 + physA * 8] = o;
      if (k < 30) {
        const int kg = (k + 2) * 32;
        vulN = *(const uint4*)(pUL + kg);
        vucN = *(const uint4*)(pUL + 1024 + kg);
        vueN = *(const uint4*)(pUE + kg);
      }
    }
    __builtin_amdgcn_sched_barrier(0);
    frag8 a[4], b[4];
    #pragma unroll
    for (int i = 0; i < 4; ++i) a[i] = *(const frag8*)&As2[cur * 4096 + aoff + i * 512];
    #pragma unroll
    for (int j = 0; j < 4; ++j) b[j] = *(const frag8*)&Bs2[cur * 8192 + boff + j * 512];
    __builtin_amdgcn_s_setprio(1);
    #pragma unroll
    for (int i = 0; i < 4; ++i)
      #pragma unroll
      for (int j = 0; j < 4; ++j)
        acc[i][j] = __builtin_amdgcn_mfma_f32_16x16x32_f16(a[i], b[j], acc[i][j], 0, 0, 0);
    __builtin_amdgcn_s_setprio(0);
    __builtin_amdgcn_sched_barrier(0);
    if (k < 30)       { asm volatile("s_waitcnt vmcnt(3)" ::: "memory"); }  // a16(k+1) landed
    else if (k == 30) { asm volatile("s_waitcnt vmcnt(0)" ::: "memory"); }  // drain a16(31)
    __builtin_amdgcn_sched_barrier(0);
  }

  // ---- epilogue: bias + relu + W3 over 256 cols -> atomicAdd partials to out ----
  __syncthreads();                                 // all LDS reads done; overlay red
  float* redf = (float*)As2;                       // 128 rows x 4 wn x 2 = 4 KiB

  float bj[4], w0v[4], w1v[4];
  #pragma unroll
  for (int j = 0; j < 4; ++j) {
    const int col = bn * 256 + wn * 64 + j * 16 + arow;
    bj[j]  = bias[col];
    w0v[j] = W3[col];
    w1v[j] = W3[H2 + col];
  }
  const int grp = lane >> 4;
  #pragma unroll
  for (int i = 0; i < 4; ++i)
    #pragma unroll
    for (int r = 0; r < 4; ++r) {
      float q0 = 0.f, q1 = 0.f;
      #pragma unroll
      for (int j = 0; j < 4; ++j) {
        float v = acc[i][j][r] + bj[j];
        v = v > 0.f ? v : 0.f;
        q0 = fmaf(v, w0v[j], q0);
        q1 = fmaf(v, w1v[j], q1);
      }
      #pragma unroll
      for (int m = 1; m < 16; m <<= 1) { q0 += __shfl_xor(q0, m); q1 += __shfl_xor(q1, m); }
      if (arow == 0) {
        const int rl = wm * 64 + i * 16 + grp * 4 + r;
        redf[(rl * 4 + wn) * 2]     = q0;
        redf[(rl * 4 + wn) * 2 + 1] = q1;
      }
    }
  __syncthreads();
  if (tid < 256) {
    const int rl = tid >> 1, s = tid & 1;
    const float v = redf[(rl * 4 + 0) * 2 + s] + redf[(rl * 4 + 1) * 2 + s]
                  + redf[(rl * 4 + 2) * 2 + s] + redf[(rl * 4 + 3) * 2 + s];
    const int row = bm * 128 + rl;
    const int b   = row / NPAD;
    const int rr  = row - b * NPAD;
    if (rr < NCAND) atomicAdd(out + ((size_t)b * NCAND + rr) * 2 + s, v);
  }
}

// ---------------- launch ----------------
extern "C" void kernel_launch(void* const* d_in, const int* in_sizes, int n_in,
                              void* d_out, int out_size, void* d_ws, size_t ws_size,
                              hipStream_t stream)
{
  const float* doc = (const float*)d_in[0];
  const float* qe  = (const float*)d_in[1];
  const float* W1  = (const float*)d_in[2];
  const float* g1  = (const float*)d_in[3];
  const float* b1  = (const float*)d_in[4];
  const float* m1  = (const float*)d_in[5];
  const float* v1  = (const float*)d_in[6];
  const float* W2  = (const float*)d_in[7];
  const float* g2  = (const float*)d_in[8];
  const float* b2  = (const float*)d_in[9];
  const float* m2  = (const float*)d_in[10];
  const float* v2  = (const float*)d_in[11];
  const float* W3  = (const float*)d_in[12];
  float* out = (float*)d_out;

  char* ws = (char*)d_ws;
  size_t off = 0;
  auto alloc = [&](size_t bytes) -> void* {
    void* p = ws + off;
    off = (off + bytes + 255) & ~(size_t)255;
    return p;
  };
  unsigned short* Fz    = (unsigned short*)alloc((size_t)TPAD * KS * 2);
  unsigned short* Rz    = (unsigned short*)alloc((size_t)TPAD * KS * 2);
  unsigned short* Wlc   = (unsigned short*)alloc((size_t)2048 * KS * 2);
  unsigned short* Wr    = (unsigned short*)alloc((size_t)1024 * KS * 2);
  unsigned short* W2b   = (unsigned short*)alloc((size_t)H2 * H1 * 2);
  float*          bias2 = (float*)alloc((size_t)H2 * 4);
  float*          baseW = (float*)alloc((size_t)BATCH * 2048 * 4);
  unsigned short* UF    = (unsigned short*)alloc((size_t)TPAD * 2048 * 2);
  unsigned short* UCR   = (unsigned short*)alloc((size_t)TPAD * 1024 * 2);   // TPAD rows (paired blocks write padded tile space)
  unsigned int*   rowmap= (unsigned int*)alloc((size_t)MROWS_F * 4);
  (void)ws_size;

  // 1. fused prep (scan + qf/baseW + weight folds + rowmap)
  k_prep<<<dim3(MP_TOTAL), 256, 0, stream>>>(doc, qe, W1, g1, b1, m1, v1,
                                             W2, g2, b2, m2, v2,
                                             Fz, Rz, Wlc, Wr, W2b, bias2, baseW, rowmap);
  // 2. fused U-table GEMMs with UCR merged (k_ucr + UR array deleted)
  k_ugemm<<<dim3(416), 256, 0, stream>>>(Fz, Wlc, Rz, Wr, baseW, UF, UCR);
  // 3. fused GEMM2: fp16 packed combine, atomics direct to out
  k_gemm2f<<<dim3(808), 512, 0, stream>>>(UF, UCR, W2b, rowmap, bias2, W3, out);
}